// Round 2
// baseline (4430.219 us; speedup 1.0000x reference)
//
#include <hip/hip_runtime.h>
#include <hip/hip_bf16.h>
#include <math.h>

#define H_SIZE 768
#define N_HEADS 12
#define HEAD 64
#define INTER 3072
#define N_LAYERS 6
#define BATCH 4
#define SEQ 2048
#define BS (BATCH*SEQ)
#define EPSV 1e-6f

typedef __attribute__((ext_vector_type(8))) short bf16x8;
typedef __attribute__((ext_vector_type(4))) float f32x4;
typedef unsigned short u16;

__device__ inline float bf2f(u16 v) {
    union { float f; unsigned u; } x; x.u = ((unsigned)v) << 16; return x.f;
}
__device__ inline u16 f2bf(float f) {
    union { float f; unsigned u; } x; x.f = f;
    unsigned u = x.u;
    return (u16)((u + 0x7FFFu + ((u >> 16) & 1u)) >> 16);
}

// ---------------- dtype probe ----------------
// flags[0]=1 if float inputs are f32 on device (else bf16); flags[1]=1 if tokens int64.
__global__ void probe_kernel(const u16* __restrict__ embed, const int* __restrict__ tokens,
                             int* __restrict__ flags) {
    if (threadIdx.x == 0 && blockIdx.x == 0) {
        int good = 0, evenzero = 0;
        for (int i = 0; i < 128; i++) {
            u16 h = embed[i];
            int e = (h >> 7) & 0xFF;
            if (h == 0 || (e >= 87 && e <= 133)) good++;   // |v| in [2^-40, 2^6] or 0
            if ((i & 1) == 0 && h == 0) evenzero++;
        }
        // bf16 buffer: good=128, evenzero~0.  f32 buffer: good~75.  bf16-rounded f32: evenzero=64.
        flags[0] = (evenzero >= 48) ? 1 : ((good >= 110) ? 0 : 1);
        int z = 0;
        for (int i = 0; i < 64; i++) if (tokens[2 * i + 1] == 0) z++;
        flags[1] = (z >= 60) ? 1 : 0;
    }
}

// ---------------- sincos table ----------------
__global__ __launch_bounds__(256) void sincos_kernel(const void* __restrict__ ages,
                                                     float* __restrict__ SIN,
                                                     float* __restrict__ COS,
                                                     const int* __restrict__ flags) {
    int idx = blockIdx.x * 256 + threadIdx.x;   // BS*32 entries
    if (idx >= BS * 32) return;
    bool f32in = flags[0] != 0;
    int row = idx >> 5, f = idx & 31;
    float age = f32in ? ((const float*)ages)[row] : bf2f(((const u16*)ages)[row]);
    float inv = expf(-(2.0f * (float)f / 31.0f) * 9.210340371976184f); // ln(10000)
    float t = age * inv;
    SIN[idx] = sinf(t);
    COS[idx] = cosf(t);
}

// ---------------- embed gather + rmsnorm (f32 out) ----------------
__global__ __launch_bounds__(256) void embed_norm_kernel(const int* __restrict__ tokens,
                                                         const void* __restrict__ embed,
                                                         const void* __restrict__ wbase,
                                                         float* __restrict__ X,
                                                         const int* __restrict__ flags) {
    int row = blockIdx.x * 4 + (threadIdx.x >> 6);
    int lane = threadIdx.x & 63;
    bool f32in = flags[0] != 0;
    bool i64 = flags[1] != 0;
    int tok = i64 ? tokens[2 * row] : tokens[row];
    tok &= 65535;
    const u16* er16 = (const u16*)embed + (size_t)tok * H_SIZE;
    const float* er32 = (const float*)embed + (size_t)tok * H_SIZE;
    const u16* w16 = (const u16*)wbase;
    const float* w32 = (const float*)wbase;
    float v[12]; float ss = 0.f;
#pragma unroll
    for (int k = 0; k < 12; k++) {
        int i = lane + k * 64;
        float t = f32in ? er32[i] : bf2f(er16[i]);
        v[k] = t; ss += t * t;
    }
#pragma unroll
    for (int off = 1; off < 64; off <<= 1) ss += __shfl_xor(ss, off, 64);
    float scale = rsqrtf(ss * (1.0f / 768.0f) + EPSV);
#pragma unroll
    for (int k = 0; k < 12; k++) {
        int i = lane + k * 64;
        float wv = f32in ? w32[i] : bf2f(w16[i]);
        X[(size_t)row * H_SIZE + i] = v[k] * scale * wv;
    }
}

// ---------------- rmsnorm f32 -> bf16 (layers) or flag-typed output (final) ----------------
// outMode 0: Y is u16 always.  outMode 1: Y is float if flags[0] else u16.
__global__ __launch_bounds__(256) void rmsnorm_kernel(const float* __restrict__ X,
                                                      const void* __restrict__ wbase, size_t woff,
                                                      void* __restrict__ Y, int outMode,
                                                      const int* __restrict__ flags) {
    int row = blockIdx.x * 4 + (threadIdx.x >> 6);
    int lane = threadIdx.x & 63;
    bool f32in = flags[0] != 0;
    const u16* w16 = (const u16*)wbase + woff;
    const float* w32 = (const float*)wbase + woff;
    const float* xr = X + (size_t)row * H_SIZE;
    float v[12]; float ss = 0.f;
#pragma unroll
    for (int k = 0; k < 12; k++) { v[k] = xr[lane + k * 64]; ss += v[k] * v[k]; }
#pragma unroll
    for (int off = 1; off < 64; off <<= 1) ss += __shfl_xor(ss, off, 64);
    float scale = rsqrtf(ss * (1.0f / 768.0f) + EPSV);
    bool of32 = outMode && f32in;
#pragma unroll
    for (int k = 0; k < 12; k++) {
        int i = lane + k * 64;
        float wv = f32in ? w32[i] : bf2f(w16[i]);
        float val = v[k] * scale * wv;
        if (of32) ((float*)Y)[(size_t)row * H_SIZE + i] = val;
        else      ((u16*)Y)[(size_t)row * H_SIZE + i] = f2bf(val);
    }
}

// ---------------- generic bf16 MFMA GEMM: C[M,N] = A[M,K] * W[K,N] + bias ----------------
// EPI 0: bf16 store to Cb (ldcb).  EPI 1: gelu -> bf16 to Cb (ldcb).  EPI 2: Cf[m*N+n] += v.
template <int EPI>
__global__ __launch_bounds__(256) void gemm_kernel(const u16* __restrict__ A,
                                                   const void* __restrict__ Wbase, size_t woff,
                                                   const void* __restrict__ Bbase, size_t boff,
                                                   float* __restrict__ Cf,
                                                   u16* __restrict__ Cb, int ldcb,
                                                   int M, int N, int K,
                                                   const int* __restrict__ flags) {
    __shared__ u16 Alds[128][40];
    __shared__ u16 Blds[128][40];   // [n][k] (transposed)
    const int tid = threadIdx.x;
    const int lane = tid & 63, wave = tid >> 6;
    const int wm = wave >> 1, wn = wave & 1;
    const int lm = lane & 15, g = lane >> 4;
    const int m0 = blockIdx.y * 128, n0 = blockIdx.x * 128;
    const bool wf32 = flags[0] != 0;
    const u16* W16 = (const u16*)Wbase + woff;
    const float* W32 = (const float*)Wbase + woff;

    f32x4 acc[4][4];
#pragma unroll
    for (int i = 0; i < 4; i++)
#pragma unroll
        for (int j = 0; j < 4; j++) acc[i][j] = (f32x4)0.0f;

    for (int k0 = 0; k0 < K; k0 += 32) {
        __syncthreads();
#pragma unroll
        for (int it = 0; it < 2; ++it) {   // A tile 128x32 (bf16 always)
            int idx = tid + it * 256;
            int r = idx >> 2, q = (idx & 3) * 8;
            uint4 v = *(const uint4*)(A + (size_t)(m0 + r) * K + k0 + q);
            *(uint4*)(&Alds[r][q]) = v;
        }
#pragma unroll
        for (int it = 0; it < 2; ++it) {   // W tile 32x128 -> transposed
            int idx = tid + it * 256;
            int r = idx >> 4, q = (idx & 15) * 8;
            if (!wf32) {
                uint4 v = *(const uint4*)(W16 + (size_t)(k0 + r) * N + n0 + q);
                const u16* pv = (const u16*)&v;
#pragma unroll
                for (int i = 0; i < 8; i++) Blds[q + i][r] = pv[i];
            } else {
                const float* src = W32 + (size_t)(k0 + r) * N + n0 + q;
                float4 f0 = *(const float4*)(src);
                float4 f1 = *(const float4*)(src + 4);
                Blds[q + 0][r] = f2bf(f0.x); Blds[q + 1][r] = f2bf(f0.y);
                Blds[q + 2][r] = f2bf(f0.z); Blds[q + 3][r] = f2bf(f0.w);
                Blds[q + 4][r] = f2bf(f1.x); Blds[q + 5][r] = f2bf(f1.y);
                Blds[q + 6][r] = f2bf(f1.z); Blds[q + 7][r] = f2bf(f1.w);
            }
        }
        __syncthreads();
        bf16x8 a[4], b[4];
#pragma unroll
        for (int i = 0; i < 4; i++) a[i] = *(const bf16x8*)(&Alds[wm * 64 + i * 16 + lm][g * 8]);
#pragma unroll
        for (int j = 0; j < 4; j++) b[j] = *(const bf16x8*)(&Blds[wn * 64 + j * 16 + lm][g * 8]);
#pragma unroll
        for (int i = 0; i < 4; i++)
#pragma unroll
            for (int j = 0; j < 4; j++)
                acc[i][j] = __builtin_amdgcn_mfma_f32_16x16x32_bf16(a[i], b[j], acc[i][j], 0, 0, 0);
    }

    const u16* B16 = (const u16*)Bbase + boff;
    const float* B32 = (const float*)Bbase + boff;
#pragma unroll
    for (int i = 0; i < 4; i++) {
        int mbase = m0 + wm * 64 + i * 16 + g * 4;
#pragma unroll
        for (int j = 0; j < 4; j++) {
            int n = n0 + wn * 64 + j * 16 + lm;
            float bv = wf32 ? B32[n] : bf2f(B16[n]);
#pragma unroll
            for (int r = 0; r < 4; r++) {
                float v = acc[i][j][r] + bv;
                int mm = mbase + r;
                if (EPI == 0) {
                    Cb[(size_t)mm * ldcb + n] = f2bf(v);
                } else if (EPI == 1) {
                    float gl = 0.5f * v * (1.0f + erff(v * 0.7071067811865475f));
                    Cb[(size_t)mm * ldcb + n] = f2bf(gl);
                } else {
                    Cf[(size_t)mm * N + n] += v;
                }
            }
        }
    }
}

// ---------------- rope in-place on bf16 qkv [row][2304] ----------------
__global__ __launch_bounds__(256) void rope_kernel(u16* __restrict__ qkv,
                                                   const float* __restrict__ SIN,
                                                   const float* __restrict__ COS) {
    int row = blockIdx.x;
    int t = threadIdx.x;
    u16* qrow = qkv + (size_t)row * 2304;
    for (int p = t; p < 384; p += 256) {
        int head = p >> 5, f = p & 31;
        float s = SIN[row * 32 + f], c = COS[row * 32 + f];
        int base = head * 64 + 2 * f;
        float q1 = bf2f(qrow[base]), q2 = bf2f(qrow[base + 1]);
        qrow[base]       = f2bf(q1 * c - q2 * s);
        qrow[base + 1]   = f2bf(q2 * c + q1 * s);
        float k1 = bf2f(qrow[768 + base]), k2 = bf2f(qrow[768 + base + 1]);
        qrow[768 + base]     = f2bf(k1 * c - k2 * s);
        qrow[768 + base + 1] = f2bf(k2 * c + k1 * s);
    }
}

// ---------------- windowed flash attention: keys j in [max(0,i-511), i] ----------------
// grid (SEQ/64, N_HEADS, BATCH), 4 waves; each wave owns 16 queries. qkv strided 2304.
__global__ __launch_bounds__(256) void attn_kernel(const u16* __restrict__ qkv,
                                                   u16* __restrict__ Out /*combined base*/) {
    __shared__ u16 Qs[64][72];
    __shared__ u16 Ks[64][72];
    __shared__ u16 Vt[64][72];      // [d][key]
    __shared__ u16 Ps[4][16][72];

    const int tid = threadIdx.x;
    const int lane = tid & 63, wave = tid >> 6;
    const int lm = lane & 15, g = lane >> 4;
    const int q0 = blockIdx.x * 64;
    const int h = blockIdx.y;
    const int b = blockIdx.z;
    const size_t rowbase = (size_t)b * SEQ;

#pragma unroll
    for (int it = 0; it < 2; ++it) {
        int idx = tid + it * 256;
        int r = idx >> 3, u = (idx & 7) * 8;
        uint4 v = *(const uint4*)(qkv + (rowbase + q0 + r) * 2304 + h * HEAD + u);
        *(uint4*)(&Qs[r][u]) = v;
    }

    float m_r[4], l_r[4];
    f32x4 o[4];
#pragma unroll
    for (int r = 0; r < 4; r++) { m_r[r] = -INFINITY; l_r[r] = 0.f; }
#pragma unroll
    for (int d = 0; d < 4; d++) o[d] = (f32x4)0.0f;

    for (int c = 0; c < 9; ++c) {
        int kc = q0 - 512 + c * 64;
        __syncthreads();
#pragma unroll
        for (int it = 0; it < 2; ++it) {
            int idx = tid + it * 256;
            int r = idx >> 3, u = (idx & 7) * 8;
            int j = kc + r;
            uint4 kv = make_uint4(0, 0, 0, 0), vv = make_uint4(0, 0, 0, 0);
            if (j >= 0) {
                kv = *(const uint4*)(qkv + (rowbase + j) * 2304 + 768 + h * HEAD + u);
                vv = *(const uint4*)(qkv + (rowbase + j) * 2304 + 1536 + h * HEAD + u);
            }
            *(uint4*)(&Ks[r][u]) = kv;
            const u16* pv = (const u16*)&vv;
#pragma unroll
            for (int i = 0; i < 8; i++) Vt[u + i][r] = pv[i];
        }
        __syncthreads();

        bf16x8 aq0 = *(const bf16x8*)(&Qs[wave * 16 + lm][g * 8]);
        bf16x8 aq1 = *(const bf16x8*)(&Qs[wave * 16 + lm][32 + g * 8]);
        f32x4 s[4];
#pragma unroll
        for (int kf = 0; kf < 4; kf++) {
            bf16x8 b0 = *(const bf16x8*)(&Ks[kf * 16 + lm][g * 8]);
            bf16x8 b1 = *(const bf16x8*)(&Ks[kf * 16 + lm][32 + g * 8]);
            f32x4 z = (f32x4)0.0f;
            z = __builtin_amdgcn_mfma_f32_16x16x32_bf16(aq0, b0, z, 0, 0, 0);
            z = __builtin_amdgcn_mfma_f32_16x16x32_bf16(aq1, b1, z, 0, 0, 0);
            s[kf] = z;
        }

        float sv[4][4], mc[4];
#pragma unroll
        for (int r = 0; r < 4; r++) mc[r] = -INFINITY;
#pragma unroll
        for (int kf = 0; kf < 4; kf++) {
            int j = kc + kf * 16 + lm;
#pragma unroll
            for (int r = 0; r < 4; r++) {
                int i = q0 + wave * 16 + g * 4 + r;
                bool valid = (j >= 0) && (j <= i) && (j >= i - 511);
                float v = valid ? s[kf][r] * 0.125f : -INFINITY;
                sv[kf][r] = v;
                mc[r] = fmaxf(mc[r], v);
            }
        }
#pragma unroll
        for (int off = 1; off < 16; off <<= 1)
#pragma unroll
            for (int r = 0; r < 4; r++) mc[r] = fmaxf(mc[r], __shfl_xor(mc[r], off, 64));

        float alpha[4], mn[4];
#pragma unroll
        for (int r = 0; r < 4; r++) {
            mn[r] = fmaxf(m_r[r], mc[r]);
            alpha[r] = (mn[r] > -1e37f) ? expf(m_r[r] - mn[r]) : 1.0f;
            m_r[r] = mn[r];
        }
        float ps[4][4], rs[4] = {0.f, 0.f, 0.f, 0.f};
#pragma unroll
        for (int kf = 0; kf < 4; kf++)
#pragma unroll
            for (int r = 0; r < 4; r++) {
                float p = (sv[kf][r] > -1e37f) ? expf(sv[kf][r] - mn[r]) : 0.0f;
                ps[kf][r] = p;
                rs[r] += p;
            }
#pragma unroll
        for (int off = 1; off < 16; off <<= 1)
#pragma unroll
            for (int r = 0; r < 4; r++) rs[r] += __shfl_xor(rs[r], off, 64);
#pragma unroll
        for (int r = 0; r < 4; r++) l_r[r] = l_r[r] * alpha[r] + rs[r];

#pragma unroll
        for (int kf = 0; kf < 4; kf++)
#pragma unroll
            for (int r = 0; r < 4; r++) Ps[wave][g * 4 + r][kf * 16 + lm] = f2bf(ps[kf][r]);

#pragma unroll
        for (int d = 0; d < 4; d++)
#pragma unroll
            for (int r = 0; r < 4; r++) o[d][r] *= alpha[r];

        bf16x8 pa0 = *(const bf16x8*)(&Ps[wave][lm][g * 8]);
        bf16x8 pa1 = *(const bf16x8*)(&Ps[wave][lm][32 + g * 8]);
#pragma unroll
        for (int d = 0; d < 4; d++) {
            bf16x8 b0 = *(const bf16x8*)(&Vt[d * 16 + lm][g * 8]);
            bf16x8 b1 = *(const bf16x8*)(&Vt[d * 16 + lm][32 + g * 8]);
            o[d] = __builtin_amdgcn_mfma_f32_16x16x32_bf16(pa0, b0, o[d], 0, 0, 0);
            o[d] = __builtin_amdgcn_mfma_f32_16x16x32_bf16(pa1, b1, o[d], 0, 0, 0);
        }
    }

#pragma unroll
    for (int d = 0; d < 4; d++) {
        int dd = d * 16 + lm;
#pragma unroll
        for (int r = 0; r < 4; r++) {
            int i = q0 + wave * 16 + g * 4 + r;
            float v = o[d][r] / l_r[r];
            Out[(rowbase + i) * 3840 + h * HEAD + dd] = f2bf(v);
        }
    }
}

extern "C" void kernel_launch(void* const* d_in, const int* in_sizes, int n_in,
                              void* d_out, int out_size, void* d_ws, size_t ws_size,
                              hipStream_t stream) {
    const int* tokens   = (const int*)d_in[0];
    const void* ages    = d_in[1];
    const void* embed   = d_in[2];
    const void* in_norm_w  = d_in[3];
    const void* out_norm_w = d_in[4];
    const void* norm_w     = d_in[5];
    const void* attn_W     = d_in[6];
    const void* attn_b     = d_in[7];
    const void* in_W       = d_in[8];
    const void* in_b       = d_in[9];
    const void* out_W      = d_in[10];
    const void* out_b      = d_in[11];

    char* w = (char*)d_ws;
    int* flags  = (int*)w;   w += 256;
    float* x    = (float*)w; w += (size_t)BS * H_SIZE * 4;
    u16* xn     = (u16*)w;   w += (size_t)BS * H_SIZE * 2;
    u16* qkv    = (u16*)w;   w += (size_t)BS * 2304 * 2;
    u16* comb   = (u16*)w;   w += (size_t)BS * 3840 * 2;
    float* sinb = (float*)w; w += (size_t)BS * 32 * 4;
    float* cosb = (float*)w; w += (size_t)BS * 32 * 4;

    probe_kernel<<<1, 64, 0, stream>>>((const u16*)embed, tokens, flags);
    sincos_kernel<<<(BS * 32 + 255) / 256, 256, 0, stream>>>(ages, sinb, cosb, flags);
    embed_norm_kernel<<<BS / 4, 256, 0, stream>>>(tokens, embed, in_norm_w, x, flags);

    for (int l = 0; l < N_LAYERS; ++l) {
        rmsnorm_kernel<<<BS / 4, 256, 0, stream>>>(x, norm_w, (size_t)l * H_SIZE, xn, 0, flags);
        gemm_kernel<0><<<dim3(2304 / 128, BS / 128), 256, 0, stream>>>(
            xn, attn_W, (size_t)l * H_SIZE * 2304, attn_b, (size_t)l * 2304,
            nullptr, qkv, 2304, BS, 2304, H_SIZE, flags);
        rope_kernel<<<BS, 256, 0, stream>>>(qkv, sinb, cosb);
        attn_kernel<<<dim3(SEQ / 64, N_HEADS, BATCH), 256, 0, stream>>>(qkv, comb);
        gemm_kernel<1><<<dim3(INTER / 128, BS / 128), 256, 0, stream>>>(
            xn, in_W, (size_t)l * H_SIZE * INTER, in_b, (size_t)l * INTER,
            nullptr, comb + H_SIZE, H_SIZE + INTER, BS, INTER, H_SIZE, flags);
        gemm_kernel<2><<<dim3(H_SIZE / 128, BS / 128), 256, 0, stream>>>(
            comb, out_W, (size_t)l * (H_SIZE + INTER) * H_SIZE, out_b, (size_t)l * H_SIZE,
            x, nullptr, 0, BS, H_SIZE, H_SIZE + INTER, flags);
    }
    rmsnorm_kernel<<<BS / 4, 256, 0, stream>>>(x, out_norm_w, 0, d_out, 1, flags);
}

// Round 3
// 2013.743 us; speedup vs baseline: 2.2000x; 2.2000x over previous
//
#include <hip/hip_runtime.h>
#include <hip/hip_bf16.h>
#include <math.h>

#define H_SIZE 768
#define N_HEADS 12
#define HEAD 64
#define INTER 3072
#define N_LAYERS 6
#define BATCH 4
#define SEQ 2048
#define BS (BATCH*SEQ)
#define EPSV 1e-6f

typedef __attribute__((ext_vector_type(8))) short bf16x8;
typedef __attribute__((ext_vector_type(4))) float f32x4;
typedef unsigned short u16;

__device__ inline float bf2f(u16 v) {
    union { float f; unsigned u; } x; x.u = ((unsigned)v) << 16; return x.f;
}
__device__ inline u16 f2bf(float f) {
    union { float f; unsigned u; } x; x.f = f;
    unsigned u = x.u;
    return (u16)((u + 0x7FFFu + ((u >> 16) & 1u)) >> 16);
}

// ---------------- dtype probe ----------------
__global__ void probe_kernel(const u16* __restrict__ embed, const int* __restrict__ tokens,
                             int* __restrict__ flags) {
    if (threadIdx.x == 0 && blockIdx.x == 0) {
        int good = 0, evenzero = 0;
        for (int i = 0; i < 128; i++) {
            u16 h = embed[i];
            int e = (h >> 7) & 0xFF;
            if (h == 0 || (e >= 87 && e <= 133)) good++;
            if ((i & 1) == 0 && h == 0) evenzero++;
        }
        flags[0] = (evenzero >= 48) ? 1 : ((good >= 110) ? 0 : 1);
        int z = 0;
        for (int i = 0; i < 64; i++) if (tokens[2 * i + 1] == 0) z++;
        flags[1] = (z >= 60) ? 1 : 0;
    }
}

// ---------------- sincos table ----------------
__global__ __launch_bounds__(256) void sincos_kernel(const void* __restrict__ ages,
                                                     float* __restrict__ SIN,
                                                     float* __restrict__ COS,
                                                     const int* __restrict__ flags) {
    int idx = blockIdx.x * 256 + threadIdx.x;
    if (idx >= BS * 32) return;
    bool f32in = flags[0] != 0;
    int row = idx >> 5, f = idx & 31;
    float age = f32in ? ((const float*)ages)[row] : bf2f(((const u16*)ages)[row]);
    float inv = expf(-(2.0f * (float)f / 31.0f) * 9.210340371976184f);
    float t = age * inv;
    SIN[idx] = sinf(t);
    COS[idx] = cosf(t);
}

// ---------------- weight transpose+convert: W[K][N] (f32|bf16) -> Wt[N][K] bf16 ----------------
__global__ __launch_bounds__(256) void wtrans_kernel(const void* __restrict__ Wsrc,
                                                     u16* __restrict__ Wt,
                                                     int K, int N,
                                                     const int* __restrict__ flags) {
    __shared__ u16 tile[64][72];
    bool f32in = flags[0] != 0;
    int k0 = blockIdx.y * 64, n0 = blockIdx.x * 64;
    int t = threadIdx.x;
    int kk = t >> 3, nn = (t & 7) * 8;
#pragma unroll
    for (int it = 0; it < 2; it++) {
        int kr = kk + it * 32;
        u16 tmp[8];
        if (f32in) {
            const float* src = (const float*)Wsrc + (size_t)(k0 + kr) * N + n0 + nn;
            float4 f0 = *(const float4*)src, f1 = *(const float4*)(src + 4);
            tmp[0] = f2bf(f0.x); tmp[1] = f2bf(f0.y); tmp[2] = f2bf(f0.z); tmp[3] = f2bf(f0.w);
            tmp[4] = f2bf(f1.x); tmp[5] = f2bf(f1.y); tmp[6] = f2bf(f1.z); tmp[7] = f2bf(f1.w);
        } else {
            uint4 v = *(const uint4*)((const u16*)Wsrc + (size_t)(k0 + kr) * N + n0 + nn);
            const u16* pv = (const u16*)&v;
#pragma unroll
            for (int i = 0; i < 8; i++) tmp[i] = pv[i];
        }
        *(uint4*)(&tile[kr][nn]) = *(const uint4*)tmp;
    }
    __syncthreads();
    int n = t >> 3, kq = (t & 7) * 8;
#pragma unroll
    for (int it = 0; it < 2; it++) {
        int nr = n + it * 32;
        u16 tmp[8];
#pragma unroll
        for (int i = 0; i < 8; i++) tmp[i] = tile[kq + i][nr];
        *(uint4*)(Wt + (size_t)(n0 + nr) * K + k0 + kq) = *(const uint4*)tmp;
    }
}

// ---------------- bias convert to bf16 ----------------
__global__ __launch_bounds__(256) void bias_conv_kernel(const void* __restrict__ ab,
                                                        const void* __restrict__ ib,
                                                        const void* __restrict__ ob,
                                                        u16* __restrict__ dst,
                                                        const int* __restrict__ flags) {
    int i = blockIdx.x * 256 + threadIdx.x;
    bool f32in = flags[0] != 0;
    const int A = 6 * 2304, B = 6 * 3072, C = 6 * 768;
    if (i < A) dst[i] = f32in ? f2bf(((const float*)ab)[i]) : ((const u16*)ab)[i];
    else if (i < A + B) { int j = i - A; dst[i] = f32in ? f2bf(((const float*)ib)[j]) : ((const u16*)ib)[j]; }
    else if (i < A + B + C) { int j = i - A - B; dst[i] = f32in ? f2bf(((const float*)ob)[j]) : ((const u16*)ob)[j]; }
}

// ---------------- embed gather + rmsnorm (f32 out) ----------------
__global__ __launch_bounds__(256) void embed_norm_kernel(const int* __restrict__ tokens,
                                                         const void* __restrict__ embed,
                                                         const void* __restrict__ wbase,
                                                         float* __restrict__ X,
                                                         const int* __restrict__ flags) {
    int row = blockIdx.x * 4 + (threadIdx.x >> 6);
    int lane = threadIdx.x & 63;
    bool f32in = flags[0] != 0;
    bool i64 = flags[1] != 0;
    int tok = i64 ? tokens[2 * row] : tokens[row];
    tok &= 65535;
    const u16* er16 = (const u16*)embed + (size_t)tok * H_SIZE;
    const float* er32 = (const float*)embed + (size_t)tok * H_SIZE;
    const u16* w16 = (const u16*)wbase;
    const float* w32 = (const float*)wbase;
    float v[12]; float ss = 0.f;
#pragma unroll
    for (int k = 0; k < 12; k++) {
        int i = lane + k * 64;
        float t = f32in ? er32[i] : bf2f(er16[i]);
        v[k] = t; ss += t * t;
    }
#pragma unroll
    for (int off = 1; off < 64; off <<= 1) ss += __shfl_xor(ss, off, 64);
    float scale = rsqrtf(ss * (1.0f / 768.0f) + EPSV);
#pragma unroll
    for (int k = 0; k < 12; k++) {
        int i = lane + k * 64;
        float wv = f32in ? w32[i] : bf2f(w16[i]);
        X[(size_t)row * H_SIZE + i] = v[k] * scale * wv;
    }
}

// ---------------- rmsnorm f32 -> bf16 / flag-typed final ----------------
__global__ __launch_bounds__(256) void rmsnorm_kernel(const float* __restrict__ X,
                                                      const void* __restrict__ wbase, size_t woff,
                                                      void* __restrict__ Y, int outMode,
                                                      const int* __restrict__ flags) {
    int row = blockIdx.x * 4 + (threadIdx.x >> 6);
    int lane = threadIdx.x & 63;
    bool f32in = flags[0] != 0;
    const u16* w16 = (const u16*)wbase + woff;
    const float* w32 = (const float*)wbase + woff;
    const float* xr = X + (size_t)row * H_SIZE;
    float v[12]; float ss = 0.f;
#pragma unroll
    for (int k = 0; k < 12; k++) { v[k] = xr[lane + k * 64]; ss += v[k] * v[k]; }
#pragma unroll
    for (int off = 1; off < 64; off <<= 1) ss += __shfl_xor(ss, off, 64);
    float scale = rsqrtf(ss * (1.0f / 768.0f) + EPSV);
    bool of32 = outMode && f32in;
#pragma unroll
    for (int k = 0; k < 12; k++) {
        int i = lane + k * 64;
        float wv = f32in ? w32[i] : bf2f(w16[i]);
        float val = v[k] * scale * wv;
        if (of32) ((float*)Y)[(size_t)row * H_SIZE + i] = val;
        else      ((u16*)Y)[(size_t)row * H_SIZE + i] = f2bf(val);
    }
}

// ---------------- bf16 MFMA GEMM: C[M,N] = A[M,K] * Wt[N,K]^T + bias ----------------
// EPI 0: bf16 -> Cb (ldcb).  EPI 1: gelu bf16 -> Cb (ldcb).  EPI 2: Cf[m*N+n] += v.
template <int EPI>
__global__ __launch_bounds__(256) void gemm_kernel(const u16* __restrict__ A,
                                                   const u16* __restrict__ Wt,
                                                   const u16* __restrict__ bias,
                                                   float* __restrict__ Cf,
                                                   u16* __restrict__ Cb, int ldcb,
                                                   int M, int N, int K) {
    __shared__ u16 Al[128][40];
    __shared__ u16 Bl[128][40];
    const int tid = threadIdx.x;
    const int lane = tid & 63, wave = tid >> 6;
    const int wm = wave >> 1, wn = wave & 1;
    const int lm = lane & 15, g = lane >> 4;
    const int m0 = blockIdx.y * 128, n0 = blockIdx.x * 128;
    const int sr = tid >> 2, sq = (tid & 3) * 8;

    f32x4 acc[4][4];
#pragma unroll
    for (int i = 0; i < 4; i++)
#pragma unroll
        for (int j = 0; j < 4; j++) acc[i][j] = (f32x4)0.0f;

    const u16* Aptr = A + (size_t)(m0 + sr) * K + sq;
    const u16* Bptr = Wt + (size_t)(n0 + sr) * K + sq;
    const size_t rowK64 = (size_t)64 * K;

    uint4 pa0 = *(const uint4*)(Aptr);
    uint4 pa1 = *(const uint4*)(Aptr + rowK64);
    uint4 pb0 = *(const uint4*)(Bptr);
    uint4 pb1 = *(const uint4*)(Bptr + rowK64);

    for (int k0 = 0; k0 < K; k0 += 32) {
        __syncthreads();
        *(uint4*)(&Al[sr][sq])      = pa0;
        *(uint4*)(&Al[sr + 64][sq]) = pa1;
        *(uint4*)(&Bl[sr][sq])      = pb0;
        *(uint4*)(&Bl[sr + 64][sq]) = pb1;
        if (k0 + 32 < K) {
            pa0 = *(const uint4*)(Aptr + k0 + 32);
            pa1 = *(const uint4*)(Aptr + rowK64 + k0 + 32);
            pb0 = *(const uint4*)(Bptr + k0 + 32);
            pb1 = *(const uint4*)(Bptr + rowK64 + k0 + 32);
        }
        __syncthreads();
        bf16x8 a[4], b[4];
#pragma unroll
        for (int i = 0; i < 4; i++) a[i] = *(const bf16x8*)(&Al[wm * 64 + i * 16 + lm][g * 8]);
#pragma unroll
        for (int j = 0; j < 4; j++) b[j] = *(const bf16x8*)(&Bl[wn * 64 + j * 16 + lm][g * 8]);
#pragma unroll
        for (int i = 0; i < 4; i++)
#pragma unroll
            for (int j = 0; j < 4; j++)
                acc[i][j] = __builtin_amdgcn_mfma_f32_16x16x32_bf16(a[i], b[j], acc[i][j], 0, 0, 0);
    }

#pragma unroll
    for (int i = 0; i < 4; i++) {
        int mbase = m0 + wm * 64 + i * 16 + g * 4;
#pragma unroll
        for (int j = 0; j < 4; j++) {
            int n = n0 + wn * 64 + j * 16 + lm;
            float bv = bf2f(bias[n]);
#pragma unroll
            for (int r = 0; r < 4; r++) {
                float v = acc[i][j][r] + bv;
                int mm = mbase + r;
                if (EPI == 0) {
                    Cb[(size_t)mm * ldcb + n] = f2bf(v);
                } else if (EPI == 1) {
                    float gl = 0.5f * v * (1.0f + erff(v * 0.7071067811865475f));
                    Cb[(size_t)mm * ldcb + n] = f2bf(gl);
                } else {
                    Cf[(size_t)mm * N + n] += v;
                }
            }
        }
    }
}

// ---------------- rope in-place on bf16 qkv [row][2304] ----------------
__global__ __launch_bounds__(256) void rope_kernel(u16* __restrict__ qkv,
                                                   const float* __restrict__ SIN,
                                                   const float* __restrict__ COS) {
    int row = blockIdx.x;
    int t = threadIdx.x;
    u16* qrow = qkv + (size_t)row * 2304;
    for (int p = t; p < 384; p += 256) {
        int head = p >> 5, f = p & 31;
        float s = SIN[row * 32 + f], c = COS[row * 32 + f];
        int base = head * 64 + 2 * f;
        float q1 = bf2f(qrow[base]), q2 = bf2f(qrow[base + 1]);
        qrow[base]     = f2bf(q1 * c - q2 * s);
        qrow[base + 1] = f2bf(q2 * c + q1 * s);
        float k1 = bf2f(qrow[768 + base]), k2 = bf2f(qrow[768 + base + 1]);
        qrow[768 + base]     = f2bf(k1 * c - k2 * s);
        qrow[768 + base + 1] = f2bf(k2 * c + k1 * s);
    }
}

// ---------------- windowed flash attention ----------------
__global__ __launch_bounds__(256) void attn_kernel(const u16* __restrict__ qkv,
                                                   u16* __restrict__ Out) {
    __shared__ u16 Qs[64][72];
    __shared__ u16 Ks[64][72];
    __shared__ u16 Vt[64][72];
    __shared__ u16 Ps[4][16][72];

    const int tid = threadIdx.x;
    const int lane = tid & 63, wave = tid >> 6;
    const int lm = lane & 15, g = lane >> 4;
    const int q0 = blockIdx.x * 64;
    const int h = blockIdx.y;
    const int b = blockIdx.z;
    const size_t rowbase = (size_t)b * SEQ;

#pragma unroll
    for (int it = 0; it < 2; ++it) {
        int idx = tid + it * 256;
        int r = idx >> 3, u = (idx & 7) * 8;
        uint4 v = *(const uint4*)(qkv + (rowbase + q0 + r) * 2304 + h * HEAD + u);
        *(uint4*)(&Qs[r][u]) = v;
    }

    float m_r[4], l_r[4];
    f32x4 o[4];
#pragma unroll
    for (int r = 0; r < 4; r++) { m_r[r] = -INFINITY; l_r[r] = 0.f; }
#pragma unroll
    for (int d = 0; d < 4; d++) o[d] = (f32x4)0.0f;

    for (int c = 0; c < 9; ++c) {
        int kc = q0 - 512 + c * 64;
        __syncthreads();
#pragma unroll
        for (int it = 0; it < 2; ++it) {
            int idx = tid + it * 256;
            int r = idx >> 3, u = (idx & 7) * 8;
            int j = kc + r;
            uint4 kv = make_uint4(0, 0, 0, 0), vv = make_uint4(0, 0, 0, 0);
            if (j >= 0) {
                kv = *(const uint4*)(qkv + (rowbase + j) * 2304 + 768 + h * HEAD + u);
                vv = *(const uint4*)(qkv + (rowbase + j) * 2304 + 1536 + h * HEAD + u);
            }
            *(uint4*)(&Ks[r][u]) = kv;
            const u16* pv = (const u16*)&vv;
#pragma unroll
            for (int i = 0; i < 8; i++) Vt[u + i][r] = pv[i];
        }
        __syncthreads();

        bf16x8 aq0 = *(const bf16x8*)(&Qs[wave * 16 + lm][g * 8]);
        bf16x8 aq1 = *(const bf16x8*)(&Qs[wave * 16 + lm][32 + g * 8]);
        f32x4 s[4];
#pragma unroll
        for (int kf = 0; kf < 4; kf++) {
            bf16x8 b0 = *(const bf16x8*)(&Ks[kf * 16 + lm][g * 8]);
            bf16x8 b1 = *(const bf16x8*)(&Ks[kf * 16 + lm][32 + g * 8]);
            f32x4 z = (f32x4)0.0f;
            z = __builtin_amdgcn_mfma_f32_16x16x32_bf16(aq0, b0, z, 0, 0, 0);
            z = __builtin_amdgcn_mfma_f32_16x16x32_bf16(aq1, b1, z, 0, 0, 0);
            s[kf] = z;
        }

        float sv[4][4], mc[4];
#pragma unroll
        for (int r = 0; r < 4; r++) mc[r] = -INFINITY;
#pragma unroll
        for (int kf = 0; kf < 4; kf++) {
            int j = kc + kf * 16 + lm;
#pragma unroll
            for (int r = 0; r < 4; r++) {
                int i = q0 + wave * 16 + g * 4 + r;
                bool valid = (j >= 0) && (j <= i) && (j >= i - 511);
                float v = valid ? s[kf][r] * 0.125f : -INFINITY;
                sv[kf][r] = v;
                mc[r] = fmaxf(mc[r], v);
            }
        }
#pragma unroll
        for (int off = 1; off < 16; off <<= 1)
#pragma unroll
            for (int r = 0; r < 4; r++) mc[r] = fmaxf(mc[r], __shfl_xor(mc[r], off, 64));

        float alpha[4], mn[4];
#pragma unroll
        for (int r = 0; r < 4; r++) {
            mn[r] = fmaxf(m_r[r], mc[r]);
            alpha[r] = (mn[r] > -1e37f) ? expf(m_r[r] - mn[r]) : 1.0f;
            m_r[r] = mn[r];
        }
        float ps[4][4], rs[4] = {0.f, 0.f, 0.f, 0.f};
#pragma unroll
        for (int kf = 0; kf < 4; kf++)
#pragma unroll
            for (int r = 0; r < 4; r++) {
                float p = (sv[kf][r] > -1e37f) ? expf(sv[kf][r] - mn[r]) : 0.0f;
                ps[kf][r] = p;
                rs[r] += p;
            }
#pragma unroll
        for (int off = 1; off < 16; off <<= 1)
#pragma unroll
            for (int r = 0; r < 4; r++) rs[r] += __shfl_xor(rs[r], off, 64);
#pragma unroll
        for (int r = 0; r < 4; r++) l_r[r] = l_r[r] * alpha[r] + rs[r];

#pragma unroll
        for (int kf = 0; kf < 4; kf++)
#pragma unroll
            for (int r = 0; r < 4; r++) Ps[wave][g * 4 + r][kf * 16 + lm] = f2bf(ps[kf][r]);

#pragma unroll
        for (int d = 0; d < 4; d++)
#pragma unroll
            for (int r = 0; r < 4; r++) o[d][r] *= alpha[r];

        bf16x8 pa0 = *(const bf16x8*)(&Ps[wave][lm][g * 8]);
        bf16x8 pa1 = *(const bf16x8*)(&Ps[wave][lm][32 + g * 8]);
#pragma unroll
        for (int d = 0; d < 4; d++) {
            bf16x8 b0 = *(const bf16x8*)(&Vt[d * 16 + lm][g * 8]);
            bf16x8 b1 = *(const bf16x8*)(&Vt[d * 16 + lm][32 + g * 8]);
            o[d] = __builtin_amdgcn_mfma_f32_16x16x32_bf16(pa0, b0, o[d], 0, 0, 0);
            o[d] = __builtin_amdgcn_mfma_f32_16x16x32_bf16(pa1, b1, o[d], 0, 0, 0);
        }
    }

#pragma unroll
    for (int d = 0; d < 4; d++) {
        int dd = d * 16 + lm;
#pragma unroll
        for (int r = 0; r < 4; r++) {
            int i = q0 + wave * 16 + g * 4 + r;
            float v = o[d][r] / l_r[r];
            Out[(rowbase + i) * 3840 + h * HEAD + dd] = f2bf(v);
        }
    }
}

extern "C" void kernel_launch(void* const* d_in, const int* in_sizes, int n_in,
                              void* d_out, int out_size, void* d_ws, size_t ws_size,
                              hipStream_t stream) {
    const int* tokens   = (const int*)d_in[0];
    const void* ages    = d_in[1];
    const void* embed   = d_in[2];
    const void* in_norm_w  = d_in[3];
    const void* out_norm_w = d_in[4];
    const void* norm_w     = d_in[5];
    const void* attn_W     = d_in[6];
    const void* attn_b     = d_in[7];
    const void* in_W       = d_in[8];
    const void* in_b       = d_in[9];
    const void* out_W      = d_in[10];
    const void* out_b      = d_in[11];

    char* w = (char*)d_ws;
    int* flags  = (int*)w;   w += 256;
    float* x    = (float*)w; w += (size_t)BS * H_SIZE * 4;
    u16* xn     = (u16*)w;   w += (size_t)BS * H_SIZE * 2;
    u16* qkv    = (u16*)w;   w += (size_t)BS * 2304 * 2;
    u16* comb   = (u16*)w;   w += (size_t)BS * 3840 * 2;
    float* sinb = (float*)w; w += (size_t)BS * 32 * 4;
    float* cosb = (float*)w; w += (size_t)BS * 32 * 4;
    u16* wt     = (u16*)w;   w += (size_t)(2304*768 + 3072*768 + 768*3840) * 2;
    u16* biasb  = (u16*)w;   w += (size_t)(6*2304 + 6*3072 + 6*768) * 2;

    u16* wqkv_t = wt;
    u16* win_t  = wt + (size_t)2304 * 768;
    u16* wout_t = win_t + (size_t)3072 * 768;
    u16* ab_b = biasb;
    u16* ib_b = biasb + 6 * 2304;
    u16* ob_b = ib_b + 6 * 3072;

    probe_kernel<<<1, 64, 0, stream>>>((const u16*)embed, tokens, flags);
    sincos_kernel<<<(BS * 32 + 255) / 256, 256, 0, stream>>>(ages, sinb, cosb, flags);
    embed_norm_kernel<<<BS / 4, 256, 0, stream>>>(tokens, embed, in_norm_w, x, flags);
    bias_conv_kernel<<<(6 * (2304 + 3072 + 768) + 255) / 256, 256, 0, stream>>>(
        attn_b, in_b, out_b, biasb, flags);

    for (int l = 0; l < N_LAYERS; ++l) {
        wtrans_kernel<<<dim3(2304 / 64, 768 / 64), 256, 0, stream>>>(
            (const char*)attn_W + (size_t)l * 768 * 2304 * 4, wqkv_t, 768, 2304, flags);
        wtrans_kernel<<<dim3(3072 / 64, 768 / 64), 256, 0, stream>>>(
            (const char*)in_W + (size_t)l * 768 * 3072 * 4, win_t, 768, 3072, flags);
        wtrans_kernel<<<dim3(768 / 64, 3840 / 64), 256, 0, stream>>>(
            (const char*)out_W + (size_t)l * 3840 * 768 * 4, wout_t, 3840, 768, flags);

        rmsnorm_kernel<<<BS / 4, 256, 0, stream>>>(x, norm_w, (size_t)l * H_SIZE, xn, 0, flags);
        gemm_kernel<0><<<dim3(2304 / 128, BS / 128), 256, 0, stream>>>(
            xn, wqkv_t, ab_b + l * 2304, nullptr, qkv, 2304, BS, 2304, H_SIZE);
        rope_kernel<<<BS, 256, 0, stream>>>(qkv, sinb, cosb);
        attn_kernel<<<dim3(SEQ / 64, N_HEADS, BATCH), 256, 0, stream>>>(qkv, comb);
        gemm_kernel<1><<<dim3(INTER / 128, BS / 128), 256, 0, stream>>>(
            xn, win_t, ib_b + l * 3072, nullptr, comb + H_SIZE, H_SIZE + INTER, BS, INTER, H_SIZE);
        gemm_kernel<2><<<dim3(H_SIZE / 128, BS / 128), 256, 0, stream>>>(
            comb, wout_t, ob_b + l * 768, x, nullptr, 0, BS, H_SIZE, H_SIZE + INTER);
    }
    rmsnorm_kernel<<<BS / 4, 256, 0, stream>>>(x, out_norm_w, 0, d_out, 1, flags);
}